// Round 1
// baseline (2273.151 us; speedup 1.0000x reference)
//
#include <hip/hip_runtime.h>
#include <hip/hip_bf16.h>

typedef __hip_bfloat16  bf16;
typedef __hip_bfloat162 bf162;

#define NB 16
#define NN 4096
#define NC 512
#define SCALE 0.044194173824159216f  // 1/sqrt(512)

// ---------------------------------------------------------------------------
// Kernel 1: fused Q/K/V projection  y = sigmoid(x @ W^T + b), written in
// spatial layout [B, C, N] as bf16 (LDS-transposed epilogue, coalesced).
// Tile: 64 rows (b*N+n) x 64 cols (d), BK=16, 4x4 per thread per matrix.
// ---------------------------------------------------------------------------
__global__ __launch_bounds__(256) void proj_kernel(
    const float* __restrict__ x,
    const float* __restrict__ Wq, const float* __restrict__ bq,
    const float* __restrict__ Wk, const float* __restrict__ bk,
    const float* __restrict__ Wv, const float* __restrict__ bv,
    bf16* __restrict__ Qs, bf16* __restrict__ Ks, bf16* __restrict__ Vs)
{
    __shared__ float xs[64][17];       // [row][k]
    __shared__ float wsm[3][64][17];   // [m][d][k]
    __shared__ float tt[64][65];       // transpose staging

    const int tid = threadIdx.x;
    const int d0  = blockIdx.x * 64;
    const int r0  = blockIdx.y * 64;     // flattened (b*N + n); 64 | 4096 so b fixed
    const int b   = r0 >> 12;
    const int n0  = r0 & 4095;
    const int tx  = tid & 15;
    const int ty  = tid >> 4;

    const float* W[3]    = {Wq, Wk, Wv};
    const float* bias[3] = {bq, bk, bv};
    bf16*        outp[3] = {Qs, Ks, Vs};

    float acc[3][4][4];
    #pragma unroll
    for (int m = 0; m < 3; ++m)
        #pragma unroll
        for (int i = 0; i < 4; ++i)
            #pragma unroll
            for (int j = 0; j < 4; ++j) acc[m][i][j] = 0.0f;

    const int lrow = tid >> 2;
    const int lk4  = (tid & 3) * 4;

    for (int k0 = 0; k0 < NC; k0 += 16) {
        float4 xv = *(const float4*)(x + (size_t)(r0 + lrow) * NC + k0 + lk4);
        xs[lrow][lk4+0] = xv.x; xs[lrow][lk4+1] = xv.y;
        xs[lrow][lk4+2] = xv.z; xs[lrow][lk4+3] = xv.w;
        #pragma unroll
        for (int m = 0; m < 3; ++m) {
            float4 wv = *(const float4*)(W[m] + (size_t)(d0 + lrow) * NC + k0 + lk4);
            wsm[m][lrow][lk4+0] = wv.x; wsm[m][lrow][lk4+1] = wv.y;
            wsm[m][lrow][lk4+2] = wv.z; wsm[m][lrow][lk4+3] = wv.w;
        }
        __syncthreads();
        #pragma unroll
        for (int kk = 0; kk < 16; ++kk) {
            float a[4];
            #pragma unroll
            for (int i = 0; i < 4; ++i) a[i] = xs[ty*4+i][kk];
            #pragma unroll
            for (int m = 0; m < 3; ++m) {
                float bb[4];
                #pragma unroll
                for (int j = 0; j < 4; ++j) bb[j] = wsm[m][tx*4+j][kk];
                #pragma unroll
                for (int i = 0; i < 4; ++i)
                    #pragma unroll
                    for (int j = 0; j < 4; ++j)
                        acc[m][i][j] = fmaf(a[i], bb[j], acc[m][i][j]);
            }
        }
        __syncthreads();
    }

    // epilogue: sigmoid + transpose to [C, N] per b, bf16-packed writes
    #pragma unroll
    for (int m = 0; m < 3; ++m) {
        float bvv[4];
        #pragma unroll
        for (int j = 0; j < 4; ++j) bvv[j] = bias[m][d0 + tx*4 + j];
        #pragma unroll
        for (int i = 0; i < 4; ++i)
            #pragma unroll
            for (int j = 0; j < 4; ++j) {
                float v = acc[m][i][j] + bvv[j];
                tt[ty*4+i][tx*4+j] = 1.0f / (1.0f + __expf(-v));
            }
        __syncthreads();
        bf162* op = (bf162*)(outp[m] + ((size_t)b * NC + d0) * NN + n0);
        #pragma unroll
        for (int w = 0; w < 8; ++w) {
            int p   = tid + w * 256;   // 0..2047 row-pairs
            int col = p >> 5;          // local d
            int rp  = p & 31;          // n row-pair
            bf162 v2;
            v2.x = __float2bfloat16(tt[2*rp  ][col]);
            v2.y = __float2bfloat16(tt[2*rp+1][col]);
            op[(size_t)col * (NN/2) + rp] = v2;
        }
        __syncthreads();
    }
}

// ---------------------------------------------------------------------------
// Kernel 2: per-(b,c) attention. One block per (b,c).
//   T = Q K^T (64x64 Gram) -> S1 = col-pooled softmax (in-place in T),
//   S2 = row-pooled softmax (transposed buffer), KV = S2@V, out = S1@KV.
// LDS 49.9 KB, all lane-varying accesses stride 1 mod 32 or 2-way.
// Output written (bf16, spatial) into the Q region (safe: Q consumed first).
// ---------------------------------------------------------------------------
__global__ __launch_bounds__(256) void attn_kernel(
    const bf16* __restrict__ Qs, const bf16* __restrict__ Ks,
    const bf16* __restrict__ Vs, bf16* __restrict__ Os)
{
    __shared__ float sR1[64*65];   // K (stride 65) -> V (stride 64)
    __shared__ float sR2[64*65];   // Q (stride 65) -> S2t[64][33] + KV[32][64]
    __shared__ float sR3[64*65];   // T (stride 65); S1 probs end up in cols 0..31

#define KT_(r,c)  sR1[(r)*65+(c)]
#define VV_(r,c)  sR1[(r)*64+(c)]
#define AQ_(r,c)  sR2[(r)*65+(c)]
#define S2T_(j,r) sR2[(j)*33+(r)]
#define KV_(i,c)  sR2[64*33+(i)*64+(c)]
#define TT_(r,c)  sR3[(r)*65+(c)]

    const int tid = threadIdx.x;
    const size_t base = (size_t)blockIdx.x * NN;   // blockIdx.x = b*C + c
    const bf162* Qg = (const bf162*)(Qs + base);
    const bf162* Kg = (const bf162*)(Ks + base);
    const bf162* Vg = (const bf162*)(Vs + base);

    // phase 1: load Q, K into LDS
    #pragma unroll
    for (int w = 0; w < 8; ++w) {
        int p = tid + w * 256;
        int row = p >> 5;
        int col = 2 * (p & 31);
        float2 fq = __bfloat1622float2(Qg[p]);
        AQ_(row, col) = fq.x; AQ_(row, col+1) = fq.y;
        float2 fk = __bfloat1622float2(Kg[p]);
        KT_(row, col) = fk.x; KT_(row, col+1) = fk.y;
    }
    __syncthreads();

    // phase 2: T = Q K^T  (unscaled)
    {
        const int j  = tid & 63;
        const int i0 = (tid >> 6) * 16;
        float tacc[16];
        #pragma unroll
        for (int ii = 0; ii < 16; ++ii) tacc[ii] = 0.0f;
        for (int ph = 0; ph < 64; ++ph) {
            float kv = KT_(j, ph);                 // lanes j: stride 65, free
            #pragma unroll
            for (int ii = 0; ii < 16; ++ii)        // A broadcast within wave
                tacc[ii] = fmaf(AQ_(i0+ii, ph), kv, tacc[ii]);
        }
        #pragma unroll
        for (int ii = 0; ii < 16; ++ii) TT_(i0+ii, j) = tacc[ii];
    }
    __syncthreads();   // Q, K in LDS now dead

    // phase 3a: load V (into old K region) + S2 logits (row-pooled T, transposed)
    #pragma unroll
    for (int w = 0; w < 8; ++w) {
        int p = tid + w * 256;
        int row = p >> 5;
        int col = 2 * (p & 31);
        float2 fv = __bfloat1622float2(Vg[p]);
        VV_(row, col) = fv.x; VV_(row, col+1) = fv.y;
    }
    if (tid < 32) {
        int r = tid;
        for (int j = 0; j < 64; ++j)
            S2T_(j, r) = SCALE * 0.5f * (TT_(2*r, j) + TT_(2*r+1, j));
    }
    __syncthreads();

    // phase 3b: S1 pooled softmax in place on T rows; S2 softmax on S2t cols
    if (tid < 64) {
        int row = tid;
        float mx = -1e30f;
        for (int j = 0; j < 32; ++j) {
            float l = SCALE * 0.5f * (TT_(row, 2*j) + TT_(row, 2*j+1));
            TT_(row, j) = l;   // safe: write index j never re-read (reads are 2j,2j+1)
            mx = fmaxf(mx, l);
        }
        float s = 0.0f;
        for (int j = 0; j < 32; ++j) {
            float e = __expf(TT_(row, j) - mx); s += e; TT_(row, j) = e;
        }
        float inv = 1.0f / s;
        for (int j = 0; j < 32; ++j) TT_(row, j) *= inv;
    } else if (tid < 96) {
        int r = tid - 64;
        float mx = -1e30f;
        for (int j = 0; j < 64; ++j) mx = fmaxf(mx, S2T_(j, r));
        float s = 0.0f;
        for (int j = 0; j < 64; ++j) {
            float e = __expf(S2T_(j, r) - mx); s += e; S2T_(j, r) = e;
        }
        float inv = 1.0f / s;
        for (int j = 0; j < 64; ++j) S2T_(j, r) *= inv;
    }
    __syncthreads();

    // phase 4: KV = S2 @ V   (32 x 64)
    {
        const int ph = tid & 63;
        const int i0 = (tid >> 6) * 8;
        float a5[8];
        #pragma unroll
        for (int ii = 0; ii < 8; ++ii) a5[ii] = 0.0f;
        for (int j = 0; j < 64; ++j) {
            float vv = VV_(j, ph);                  // lanes ph: 2-way, free
            #pragma unroll
            for (int ii = 0; ii < 8; ++ii)          // S2t broadcast
                a5[ii] = fmaf(S2T_(j, i0+ii), vv, a5[ii]);
        }
        #pragma unroll
        for (int ii = 0; ii < 8; ++ii) KV_(i0+ii, ph) = a5[ii];
    }
    __syncthreads();

    // phase 5: out = S1 @ KV (64 x 64), write bf16 pairs (coalesced)
    {
        const int phh = tid & 31;       // output ph pair
        const int i0  = (tid >> 5) * 8;
        float a0[8], a1[8];
        #pragma unroll
        for (int ii = 0; ii < 8; ++ii) { a0[ii] = 0.0f; a1[ii] = 0.0f; }
        for (int j = 0; j < 32; ++j) {
            float k0v = KV_(j, 2*phh);
            float k1v = KV_(j, 2*phh+1);
            #pragma unroll
            for (int ii = 0; ii < 8; ++ii) {
                float pr = TT_(i0+ii, j);           // S1 probs, broadcast
                a0[ii] = fmaf(pr, k0v, a0[ii]);
                a1[ii] = fmaf(pr, k1v, a1[ii]);
            }
        }
        bf162* Og = (bf162*)(Os + base);
        #pragma unroll
        for (int ii = 0; ii < 8; ++ii) {
            bf162 v2;
            v2.x = __float2bfloat16(a0[ii]);
            v2.y = __float2bfloat16(a1[ii]);
            Og[(size_t)(i0+ii) * 32 + phh] = v2;
        }
    }
#undef KT_
#undef VV_
#undef AQ_
#undef S2T_
#undef KV_
#undef TT_
}

// ---------------------------------------------------------------------------
// Kernel 3: spatial [B,C,N] (bf16) -> [B,N,C] (f32) tiled transpose.
// Tile: 32 c x 64 n per block.
// ---------------------------------------------------------------------------
__global__ __launch_bounds__(256) void unspat_kernel(
    const bf16* __restrict__ Os, float* __restrict__ out)
{
    __shared__ float t[32][65];
    const int b  = blockIdx.z;
    const int c0 = blockIdx.y * 32;
    const int n0 = blockIdx.x * 64;
    const int tx = threadIdx.x & 31;
    const int ty = threadIdx.x >> 5;   // 0..7
    const bf162* src = (const bf162*)(Os + ((size_t)b * NC + c0) * NN + n0);
    #pragma unroll
    for (int r = 0; r < 4; ++r) {
        int cc = ty + r * 8;
        float2 f = __bfloat1622float2(src[(size_t)cc * (NN/2) + tx]);
        t[cc][2*tx] = f.x; t[cc][2*tx+1] = f.y;
    }
    __syncthreads();
    float* dst = out + ((size_t)b * NN + n0) * NC + c0;
    #pragma unroll
    for (int r = 0; r < 8; ++r) {
        int nn = ty + r * 8;
        dst[(size_t)nn * NC + tx] = t[tx][nn];     // read stride 65: conflict-free
    }
}

// ---------------------------------------------------------------------------
extern "C" void kernel_launch(void* const* d_in, const int* in_sizes, int n_in,
                              void* d_out, int out_size, void* d_ws, size_t ws_size,
                              hipStream_t stream)
{
    const float* x  = (const float*)d_in[0];
    const float* Wq = (const float*)d_in[1];
    const float* bq = (const float*)d_in[2];
    const float* Wk = (const float*)d_in[3];
    const float* bk = (const float*)d_in[4];
    const float* Wv = (const float*)d_in[5];
    const float* bv = (const float*)d_in[6];
    float* out = (float*)d_out;

    const size_t S = (size_t)NB * NC * NN;   // 33,554,432 elems per tensor
    bf16* Qb = (bf16*)d_ws;                  // needs ws >= 3*S*2 = 201,326,592 B
    bf16* Kb = Qb + S;
    bf16* Vb = Kb + S;

    proj_kernel<<<dim3(NC/64, (NB*NN)/64), 256, 0, stream>>>(
        x, Wq, bq, Wk, bk, Wv, bv, Qb, Kb, Vb);
    // attention writes its output into the Q region (each block consumes its
    // own Q slice into LDS before overwriting it; slices are disjoint).
    attn_kernel<<<dim3(NB*NC), 256, 0, stream>>>(Qb, Kb, Vb, Qb);
    unspat_kernel<<<dim3(NN/64, NC/32, NB), 256, 0, stream>>>(Qb, out);
}

// Round 2
// 787.252 us; speedup vs baseline: 2.8875x; 2.8875x over previous
//
#include <hip/hip_runtime.h>
#include <hip/hip_bf16.h>
#include <string.h>

typedef __hip_bfloat16  bf16;
typedef __hip_bfloat162 bf162;
typedef __attribute__((ext_vector_type(8))) short short8;
typedef __attribute__((ext_vector_type(4))) float f32x4;

#define NB 16
#define NN 4096
#define NC 512
#define SCALE 0.044194173824159216f  // 1/sqrt(512)
#define LDSTR 56                     // LDS row stride (bf16 elems): 112 B, 16B-aligned, 2-way banks

// ---------------------------------------------------------------------------
// Kernel 0: cast x [65536,512] fp32 -> bf16 (into d_out region, dead there
// until unspat_kernel overwrites it at the end).
// ---------------------------------------------------------------------------
__global__ __launch_bounds__(256) void cast_x_kernel(
    const float* __restrict__ x, bf16* __restrict__ xb)
{
    size_t i = ((size_t)blockIdx.x * 256 + threadIdx.x) * 8;
    float4 a = *(const float4*)(x + i);
    float4 b = *(const float4*)(x + i + 4);
    bf16 t[8];
    t[0] = __float2bfloat16(a.x); t[1] = __float2bfloat16(a.y);
    t[2] = __float2bfloat16(a.z); t[3] = __float2bfloat16(a.w);
    t[4] = __float2bfloat16(b.x); t[5] = __float2bfloat16(b.y);
    t[6] = __float2bfloat16(b.z); t[7] = __float2bfloat16(b.w);
    uint4 r; memcpy(&r, t, 16);
    *(uint4*)(xb + i) = r;
}

// ---------------------------------------------------------------------------
// Kernel 1: MFMA projection  y = sigmoid(xb @ W^T + b) -> spatial [B,C,N] bf16.
// 128x128 tile, BK=32, 4 waves (2x2), each wave 4x4 of mfma_f32_16x16x32_bf16.
// blockIdx.x: 12 = 3 matrices x 4 d-blocks. blockIdx.y: 512 row-blocks.
// W staged fp32->bf16 in-register (3 MB unique, L2-resident).
// ---------------------------------------------------------------------------
__global__ __launch_bounds__(256) void proj_mfma(
    const bf16* __restrict__ xb,
    const float* __restrict__ Wq, const float* __restrict__ bq,
    const float* __restrict__ Wk, const float* __restrict__ bk,
    const float* __restrict__ Wv, const float* __restrict__ bv,
    bf16* __restrict__ Qs, bf16* __restrict__ Ks, bf16* __restrict__ Vs)
{
    __shared__ __align__(16) char smem[2 * 128 * LDSTR * 2];  // 28672 B
    short* As = (short*)smem;                      // [128 rows][LDSTR]
    short* Bs = (short*)(smem + 128 * LDSTR * 2);  // [128 d]   [LDSTR]
    float* st = (float*)smem;                      // epilogue: [128 n][33] = 16896 B

    const int tid = threadIdx.x;
    const int w   = tid >> 6;     // wave 0..3
    const int l   = tid & 63;     // lane
    const int q   = l >> 4;       // quad 0..3
    const int mrow= l & 15;
    const int wr  = w >> 1;       // wave row (n)
    const int wc  = w & 1;        // wave col (d)

    const int bx = blockIdx.x;
    const int m  = bx >> 2;               // 0=Q,1=K,2=V
    const int d0 = (bx & 3) * 128;
    const int r0 = blockIdx.y * 128;      // flattened b*N+n; 128|4096 -> b fixed
    const int b  = r0 >> 12;
    const int n0 = r0 & 4095;

    const float* W    = (m == 0) ? Wq : (m == 1) ? Wk : Wv;
    const float* bias = (m == 0) ? bq : (m == 1) ? bk : bv;
    bf16*        Out  = (m == 0) ? Qs : (m == 1) ? Ks : Vs;

    f32x4 acc[4][4];
    const f32x4 z = {0.f, 0.f, 0.f, 0.f};
    #pragma unroll
    for (int i = 0; i < 4; ++i)
        #pragma unroll
        for (int j = 0; j < 4; ++j) acc[i][j] = z;

    const int srow0 = tid >> 2;          // staging row for seg i=0 (i=1: +64)
    const int kseg  = (tid & 3) * 8;     // k offset within BK (elems)

    for (int k0 = 0; k0 < NC; k0 += 32) {
        // stage A (bf16 source): 128x32 elems, 2 segs of 8 per thread
        #pragma unroll
        for (int i = 0; i < 2; ++i) {
            int srow = srow0 + 64 * i;
            uint4 av = *(const uint4*)(xb + (size_t)(r0 + srow) * NC + k0 + kseg);
            *(uint4*)&As[srow * LDSTR + kseg] = av;
        }
        // stage B (fp32 source, cvt in-register)
        #pragma unroll
        for (int i = 0; i < 2; ++i) {
            int srow = srow0 + 64 * i;
            const float* wp = W + (size_t)(d0 + srow) * NC + k0 + kseg;
            float4 w0 = *(const float4*)(wp);
            float4 w1 = *(const float4*)(wp + 4);
            bf16 t[8];
            t[0] = __float2bfloat16(w0.x); t[1] = __float2bfloat16(w0.y);
            t[2] = __float2bfloat16(w0.z); t[3] = __float2bfloat16(w0.w);
            t[4] = __float2bfloat16(w1.x); t[5] = __float2bfloat16(w1.y);
            t[6] = __float2bfloat16(w1.z); t[7] = __float2bfloat16(w1.w);
            uint4 r; memcpy(&r, t, 16);
            *(uint4*)&Bs[srow * LDSTR + kseg] = r;
        }
        __syncthreads();

        short8 af[4], bfr[4];
        #pragma unroll
        for (int ti = 0; ti < 4; ++ti)
            af[ti] = *(const short8*)&As[(64 * wr + 16 * ti + mrow) * LDSTR + q * 8];
        #pragma unroll
        for (int tj = 0; tj < 4; ++tj)
            bfr[tj] = *(const short8*)&Bs[(64 * wc + 16 * tj + mrow) * LDSTR + q * 8];
        #pragma unroll
        for (int ti = 0; ti < 4; ++ti)
            #pragma unroll
            for (int tj = 0; tj < 4; ++tj)
                acc[ti][tj] = __builtin_amdgcn_mfma_f32_16x16x32_bf16(
                    af[ti], bfr[tj], acc[ti][tj], 0, 0, 0);
        __syncthreads();
    }

    // bias per tile_j column
    float bb[4];
    #pragma unroll
    for (int tj = 0; tj < 4; ++tj) bb[tj] = bias[d0 + 64 * wc + 16 * tj + mrow];

    // epilogue: sigmoid + transpose to [C,N], 4 passes of 32 d-columns
    #pragma unroll
    for (int dc = 0; dc < 4; ++dc) {
        if (wc == (dc >> 1)) {
            #pragma unroll
            for (int tjh = 0; tjh < 2; ++tjh) {
                int tj = 2 * (dc & 1) + tjh;
                #pragma unroll
                for (int ti = 0; ti < 4; ++ti)
                    #pragma unroll
                    for (int g = 0; g < 4; ++g) {
                        float v  = acc[ti][tj][g] + bb[tj];
                        float sg = 1.0f / (1.0f + __expf(-v));
                        int nl = 64 * wr + 16 * ti + 4 * q + g;   // C/D row = n
                        int dl = 16 * tjh + mrow;                  // col within chunk
                        st[nl * 33 + dl] = sg;
                    }
            }
        }
        __syncthreads();
        #pragma unroll
        for (int i = 0; i < 8; ++i) {
            int p     = tid + 256 * i;
            int dl    = p >> 6;        // 0..31
            int npair = tid & 63;
            bf162 v2;
            v2.x = __float2bfloat16(st[(2 * npair    ) * 33 + dl]);
            v2.y = __float2bfloat16(st[(2 * npair + 1) * 33 + dl]);
            size_t d = d0 + 32 * dc + dl;
            ((bf162*)(Out + ((size_t)b * NC + d) * NN + n0))[npair] = v2;
        }
        __syncthreads();
    }
}

// ---------------------------------------------------------------------------
// Kernel 2: per-(b,c) attention (unchanged from round 1).
// ---------------------------------------------------------------------------
__global__ __launch_bounds__(256) void attn_kernel(
    const bf16* __restrict__ Qs, const bf16* __restrict__ Ks,
    const bf16* __restrict__ Vs, bf16* __restrict__ Os)
{
    __shared__ float sR1[64*65];   // K (stride 65) -> V (stride 64)
    __shared__ float sR2[64*65];   // Q (stride 65) -> S2t[64][33] + KV[32][64]
    __shared__ float sR3[64*65];   // T (stride 65); S1 probs end up in cols 0..31

#define KT_(r,c)  sR1[(r)*65+(c)]
#define VV_(r,c)  sR1[(r)*64+(c)]
#define AQ_(r,c)  sR2[(r)*65+(c)]
#define S2T_(j,r) sR2[(j)*33+(r)]
#define KV_(i,c)  sR2[64*33+(i)*64+(c)]
#define TT_(r,c)  sR3[(r)*65+(c)]

    const int tid = threadIdx.x;
    const size_t base = (size_t)blockIdx.x * NN;   // blockIdx.x = b*C + c
    const bf162* Qg = (const bf162*)(Qs + base);
    const bf162* Kg = (const bf162*)(Ks + base);
    const bf162* Vg = (const bf162*)(Vs + base);

    #pragma unroll
    for (int w = 0; w < 8; ++w) {
        int p = tid + w * 256;
        int row = p >> 5;
        int col = 2 * (p & 31);
        float2 fq = __bfloat1622float2(Qg[p]);
        AQ_(row, col) = fq.x; AQ_(row, col+1) = fq.y;
        float2 fk = __bfloat1622float2(Kg[p]);
        KT_(row, col) = fk.x; KT_(row, col+1) = fk.y;
    }
    __syncthreads();

    // T = Q K^T
    {
        const int j  = tid & 63;
        const int i0 = (tid >> 6) * 16;
        float tacc[16];
        #pragma unroll
        for (int ii = 0; ii < 16; ++ii) tacc[ii] = 0.0f;
        for (int ph = 0; ph < 64; ++ph) {
            float kv = KT_(j, ph);
            #pragma unroll
            for (int ii = 0; ii < 16; ++ii)
                tacc[ii] = fmaf(AQ_(i0+ii, ph), kv, tacc[ii]);
        }
        #pragma unroll
        for (int ii = 0; ii < 16; ++ii) TT_(i0+ii, j) = tacc[ii];
    }
    __syncthreads();

    #pragma unroll
    for (int w = 0; w < 8; ++w) {
        int p = tid + w * 256;
        int row = p >> 5;
        int col = 2 * (p & 31);
        float2 fv = __bfloat1622float2(Vg[p]);
        VV_(row, col) = fv.x; VV_(row, col+1) = fv.y;
    }
    if (tid < 32) {
        int r = tid;
        for (int j = 0; j < 64; ++j)
            S2T_(j, r) = SCALE * 0.5f * (TT_(2*r, j) + TT_(2*r+1, j));
    }
    __syncthreads();

    if (tid < 64) {
        int row = tid;
        float mx = -1e30f;
        for (int j = 0; j < 32; ++j) {
            float l = SCALE * 0.5f * (TT_(row, 2*j) + TT_(row, 2*j+1));
            TT_(row, j) = l;
            mx = fmaxf(mx, l);
        }
        float s = 0.0f;
        for (int j = 0; j < 32; ++j) {
            float e = __expf(TT_(row, j) - mx); s += e; TT_(row, j) = e;
        }
        float inv = 1.0f / s;
        for (int j = 0; j < 32; ++j) TT_(row, j) *= inv;
    } else if (tid < 96) {
        int r = tid - 64;
        float mx = -1e30f;
        for (int j = 0; j < 64; ++j) mx = fmaxf(mx, S2T_(j, r));
        float s = 0.0f;
        for (int j = 0; j < 64; ++j) {
            float e = __expf(S2T_(j, r) - mx); s += e; S2T_(j, r) = e;
        }
        float inv = 1.0f / s;
        for (int j = 0; j < 64; ++j) S2T_(j, r) *= inv;
    }
    __syncthreads();

    // KV = S2 @ V (32x64)
    {
        const int ph = tid & 63;
        const int i0 = (tid >> 6) * 8;
        float a5[8];
        #pragma unroll
        for (int ii = 0; ii < 8; ++ii) a5[ii] = 0.0f;
        for (int j = 0; j < 64; ++j) {
            float vv = VV_(j, ph);
            #pragma unroll
            for (int ii = 0; ii < 8; ++ii)
                a5[ii] = fmaf(S2T_(j, i0+ii), vv, a5[ii]);
        }
        #pragma unroll
        for (int ii = 0; ii < 8; ++ii) KV_(i0+ii, ph) = a5[ii];
    }
    __syncthreads();

    // out = S1 @ KV (64x64)
    {
        const int phh = tid & 31;
        const int i0  = (tid >> 5) * 8;
        float a0[8], a1[8];
        #pragma unroll
        for (int ii = 0; ii < 8; ++ii) { a0[ii] = 0.0f; a1[ii] = 0.0f; }
        for (int j = 0; j < 32; ++j) {
            float k0v = KV_(j, 2*phh);
            float k1v = KV_(j, 2*phh+1);
            #pragma unroll
            for (int ii = 0; ii < 8; ++ii) {
                float pr = TT_(i0+ii, j);
                a0[ii] = fmaf(pr, k0v, a0[ii]);
                a1[ii] = fmaf(pr, k1v, a1[ii]);
            }
        }
        bf162* Og = (bf162*)(Os + base);
        #pragma unroll
        for (int ii = 0; ii < 8; ++ii) {
            bf162 v2;
            v2.x = __float2bfloat16(a0[ii]);
            v2.y = __float2bfloat16(a1[ii]);
            Og[(size_t)(i0+ii) * 32 + phh] = v2;
        }
    }
#undef KT_
#undef VV_
#undef AQ_
#undef S2T_
#undef KV_
#undef TT_
}

// ---------------------------------------------------------------------------
// Kernel 3: spatial [B,C,N] (bf16) -> [B,N,C] (f32) tiled transpose.
// ---------------------------------------------------------------------------
__global__ __launch_bounds__(256) void unspat_kernel(
    const bf16* __restrict__ Os, float* __restrict__ out)
{
    __shared__ float t[32][65];
    const int b  = blockIdx.z;
    const int c0 = blockIdx.y * 32;
    const int n0 = blockIdx.x * 64;
    const int tx = threadIdx.x & 31;
    const int ty = threadIdx.x >> 5;
    const bf162* src = (const bf162*)(Os + ((size_t)b * NC + c0) * NN + n0);
    #pragma unroll
    for (int r = 0; r < 4; ++r) {
        int cc = ty + r * 8;
        float2 f = __bfloat1622float2(src[(size_t)cc * (NN/2) + tx]);
        t[cc][2*tx] = f.x; t[cc][2*tx+1] = f.y;
    }
    __syncthreads();
    float* dst = out + ((size_t)b * NN + n0) * NC + c0;
    #pragma unroll
    for (int r = 0; r < 8; ++r) {
        int nn = ty + r * 8;
        dst[(size_t)nn * NC + tx] = t[tx][nn];
    }
}

// ---------------------------------------------------------------------------
extern "C" void kernel_launch(void* const* d_in, const int* in_sizes, int n_in,
                              void* d_out, int out_size, void* d_ws, size_t ws_size,
                              hipStream_t stream)
{
    const float* x  = (const float*)d_in[0];
    const float* Wq = (const float*)d_in[1];
    const float* bq = (const float*)d_in[2];
    const float* Wk = (const float*)d_in[3];
    const float* bk = (const float*)d_in[4];
    const float* Wv = (const float*)d_in[5];
    const float* bv = (const float*)d_in[6];
    float* out = (float*)d_out;

    const size_t S = (size_t)NB * NC * NN;   // 33,554,432 elems per tensor
    bf16* Qb = (bf16*)d_ws;                  // ws >= 3*S*2 = 201,326,592 B
    bf16* Kb = Qb + S;
    bf16* Vb = Kb + S;
    // xb lives in d_out (128 MiB fp32 region; dead until unspat overwrites it)
    bf16* xb = (bf16*)d_out;

    cast_x_kernel<<<dim3((NB * NN * NC) / (256 * 8)), 256, 0, stream>>>(x, xb);
    proj_mfma<<<dim3(12, (NB * NN) / 128), 256, 0, stream>>>(
        xb, Wq, bq, Wk, bk, Wv, bv, Qb, Kb, Vb);
    // attention writes its output into the Q region (each block consumes its
    // own Q slice into LDS before overwriting it; slices are disjoint).
    attn_kernel<<<dim3(NB * NC), 256, 0, stream>>>(Qb, Kb, Vb, Qb);
    unspat_kernel<<<dim3(NN / 64, NC / 32, NB), 256, 0, stream>>>(Qb, out);
}

// Round 3
// 581.254 us; speedup vs baseline: 3.9108x; 1.3544x over previous
//
#include <hip/hip_runtime.h>
#include <hip/hip_bf16.h>
#include <string.h>

typedef __hip_bfloat16  bf16;
typedef __hip_bfloat162 bf162;
typedef __attribute__((ext_vector_type(8))) short short8;
typedef __attribute__((ext_vector_type(4))) float f32x4;

#define NB 16
#define NN 4096
#define NC 512
#define SCALE 0.044194173824159216f  // 1/sqrt(512)
#define LDSTR 56                     // proj LDS row stride (bf16 elems)

// ---------------------------------------------------------------------------
// Kernel 0: cast x [65536,512] fp32 -> bf16 (into d_out region, dead there
// until unspat_kernel overwrites it at the end).
// ---------------------------------------------------------------------------
__global__ __launch_bounds__(256) void cast_x_kernel(
    const float* __restrict__ x, bf16* __restrict__ xb)
{
    size_t i = ((size_t)blockIdx.x * 256 + threadIdx.x) * 8;
    float4 a = *(const float4*)(x + i);
    float4 b = *(const float4*)(x + i + 4);
    bf16 t[8];
    t[0] = __float2bfloat16(a.x); t[1] = __float2bfloat16(a.y);
    t[2] = __float2bfloat16(a.z); t[3] = __float2bfloat16(a.w);
    t[4] = __float2bfloat16(b.x); t[5] = __float2bfloat16(b.y);
    t[6] = __float2bfloat16(b.z); t[7] = __float2bfloat16(b.w);
    uint4 r; memcpy(&r, t, 16);
    *(uint4*)(xb + i) = r;
}

// ---------------------------------------------------------------------------
// Kernel 1: MFMA projection  y = sigmoid(xb @ W^T + b) -> spatial [B,C,N] bf16.
// (unchanged from round 2)
// ---------------------------------------------------------------------------
__global__ __launch_bounds__(256) void proj_mfma(
    const bf16* __restrict__ xb,
    const float* __restrict__ Wq, const float* __restrict__ bq,
    const float* __restrict__ Wk, const float* __restrict__ bk,
    const float* __restrict__ Wv, const float* __restrict__ bv,
    bf16* __restrict__ Qs, bf16* __restrict__ Ks, bf16* __restrict__ Vs)
{
    __shared__ __align__(16) char smem[2 * 128 * LDSTR * 2];  // 28672 B
    short* As = (short*)smem;                      // [128 rows][LDSTR]
    short* Bs = (short*)(smem + 128 * LDSTR * 2);  // [128 d]   [LDSTR]
    float* st = (float*)smem;                      // epilogue: [128 n][33]

    const int tid = threadIdx.x;
    const int w   = tid >> 6;
    const int l   = tid & 63;
    const int q   = l >> 4;
    const int mrow= l & 15;
    const int wr  = w >> 1;
    const int wc  = w & 1;

    const int bx = blockIdx.x;
    const int m  = bx >> 2;               // 0=Q,1=K,2=V
    const int d0 = (bx & 3) * 128;
    const int r0 = blockIdx.y * 128;
    const int b  = r0 >> 12;
    const int n0 = r0 & 4095;

    const float* W    = (m == 0) ? Wq : (m == 1) ? Wk : Wv;
    const float* bias = (m == 0) ? bq : (m == 1) ? bk : bv;
    bf16*        Out  = (m == 0) ? Qs : (m == 1) ? Ks : Vs;

    f32x4 acc[4][4];
    const f32x4 z = {0.f, 0.f, 0.f, 0.f};
    #pragma unroll
    for (int i = 0; i < 4; ++i)
        #pragma unroll
        for (int j = 0; j < 4; ++j) acc[i][j] = z;

    const int srow0 = tid >> 2;
    const int kseg  = (tid & 3) * 8;

    for (int k0 = 0; k0 < NC; k0 += 32) {
        #pragma unroll
        for (int i = 0; i < 2; ++i) {
            int srow = srow0 + 64 * i;
            uint4 av = *(const uint4*)(xb + (size_t)(r0 + srow) * NC + k0 + kseg);
            *(uint4*)&As[srow * LDSTR + kseg] = av;
        }
        #pragma unroll
        for (int i = 0; i < 2; ++i) {
            int srow = srow0 + 64 * i;
            const float* wp = W + (size_t)(d0 + srow) * NC + k0 + kseg;
            float4 w0 = *(const float4*)(wp);
            float4 w1 = *(const float4*)(wp + 4);
            bf16 t[8];
            t[0] = __float2bfloat16(w0.x); t[1] = __float2bfloat16(w0.y);
            t[2] = __float2bfloat16(w0.z); t[3] = __float2bfloat16(w0.w);
            t[4] = __float2bfloat16(w1.x); t[5] = __float2bfloat16(w1.y);
            t[6] = __float2bfloat16(w1.z); t[7] = __float2bfloat16(w1.w);
            uint4 r; memcpy(&r, t, 16);
            *(uint4*)&Bs[srow * LDSTR + kseg] = r;
        }
        __syncthreads();

        short8 af[4], bfr[4];
        #pragma unroll
        for (int ti = 0; ti < 4; ++ti)
            af[ti] = *(const short8*)&As[(64 * wr + 16 * ti + mrow) * LDSTR + q * 8];
        #pragma unroll
        for (int tj = 0; tj < 4; ++tj)
            bfr[tj] = *(const short8*)&Bs[(64 * wc + 16 * tj + mrow) * LDSTR + q * 8];
        #pragma unroll
        for (int ti = 0; ti < 4; ++ti)
            #pragma unroll
            for (int tj = 0; tj < 4; ++tj)
                acc[ti][tj] = __builtin_amdgcn_mfma_f32_16x16x32_bf16(
                    af[ti], bfr[tj], acc[ti][tj], 0, 0, 0);
        __syncthreads();
    }

    float bb[4];
    #pragma unroll
    for (int tj = 0; tj < 4; ++tj) bb[tj] = bias[d0 + 64 * wc + 16 * tj + mrow];

    #pragma unroll
    for (int dc = 0; dc < 4; ++dc) {
        if (wc == (dc >> 1)) {
            #pragma unroll
            for (int tjh = 0; tjh < 2; ++tjh) {
                int tj = 2 * (dc & 1) + tjh;
                #pragma unroll
                for (int ti = 0; ti < 4; ++ti)
                    #pragma unroll
                    for (int g = 0; g < 4; ++g) {
                        float v  = acc[ti][tj][g] + bb[tj];
                        float sg = 1.0f / (1.0f + __expf(-v));
                        int nl = 64 * wr + 16 * ti + 4 * q + g;
                        int dl = 16 * tjh + mrow;
                        st[nl * 33 + dl] = sg;
                    }
            }
        }
        __syncthreads();
        #pragma unroll
        for (int i = 0; i < 8; ++i) {
            int p     = tid + 256 * i;
            int dl    = p >> 6;
            int npair = tid & 63;
            bf162 v2;
            v2.x = __float2bfloat16(st[(2 * npair    ) * 33 + dl]);
            v2.y = __float2bfloat16(st[(2 * npair + 1) * 33 + dl]);
            size_t d = d0 + 32 * dc + dl;
            ((bf162*)(Out + ((size_t)b * NC + d) * NN + n0))[npair] = v2;
        }
        __syncthreads();
    }
}

// ---------------------------------------------------------------------------
// Kernel 2: MFMA attention. One block (4 waves) per (b,c).
// Wave w owns Q-row tile w (rows 16w..16w+15) of the 64x64 spatial matrix.
//   T = Q K^T         : A,B frags loaded DIRECTLY from global (spatial layout
//                       is row-major-in-K for mfma_16x16x32). C-layout regs.
//   softmaxes         : fully in-register (pool cols via shfl_xor(1); pool
//                       rows via reg pairs; reduce via xor-shuffles 1,2,4,8
//                       within the 16-lane group). Probs -> bf16 LDS.
//   KV^T = V^T @ S2^T : A = VT (LDS-transposed V), B = S2 probs. -> bf16 LDS.
//   out  = S1 @ KV    : A = S1 probs, B = KVT. C-layout -> LDS -> coalesced
//                       bf162 global store (into the Q region, slices disjoint).
// LDS 23.5 KB. C/D layout (16x16): col=lane&15, row=(lane>>4)*4+reg.
// A/B layout: row m/n = lane&15, k = (lane>>4)*8 + 0..7 (+32 per k-step).
// ---------------------------------------------------------------------------
__global__ __launch_bounds__(256) void attn_mfma(
    const bf16* __restrict__ Qs, const bf16* __restrict__ Ks,
    const bf16* __restrict__ Vs, bf16* __restrict__ Os)
{
    __shared__ __align__(16) char smem[24064];
    bf16* VT  = (bf16*)smem;                         // [64][72]; later: OutS
    bf16* S1b = (bf16*)(smem + 9216);                // [64][40]
    bf16* S2b = (bf16*)(smem + 9216 + 5120);         // [32][72]
    bf16* KVT = (bf16*)(smem + 9216 + 5120 + 4608);  // [64][40]

    const int tid = threadIdx.x;
    const int w   = tid >> 6;     // wave 0..3 -> i-tile / ph-tile
    const int l   = tid & 63;
    const int m   = l & 15;       // A/B row within tile; C col within tile
    const int q   = l >> 4;       // k-quad; C row group
    const size_t base = (size_t)blockIdx.x * NN;   // blockIdx.x = b*C + c

    // ---- phase 1: V -> VT (bf16 transpose into LDS) ----
    {
        const uint4* src = (const uint4*)(Vs + base);
        #pragma unroll
        for (int v = 0; v < 2; ++v) {
            int e = tid + 256 * v;           // 0..511, covers 8 elems each
            uint4 r = src[e];
            bf16 tmp[8]; memcpy(tmp, &r, 16);
            int pw  = e >> 3;
            int ph0 = (e & 7) * 8;
            #pragma unroll
            for (int t = 0; t < 8; ++t)
                VT[(ph0 + t) * 72 + pw] = tmp[t];
        }
    }

    // ---- phase 2: T = Q K^T (rows 16w..16w+15, all 64 cols) ----
    f32x4 tacc[4];
    {
        const f32x4 z = {0.f, 0.f, 0.f, 0.f};
        short8 aQ[2];
        #pragma unroll
        for (int ks = 0; ks < 2; ++ks)
            aQ[ks] = *(const short8*)(Qs + base + (16 * w + m) * 64 + q * 8 + 32 * ks);
        #pragma unroll
        for (int tj = 0; tj < 4; ++tj) {
            tacc[tj] = z;
            #pragma unroll
            for (int ks = 0; ks < 2; ++ks) {
                short8 bK = *(const short8*)(Ks + base + (16 * tj + m) * 64 + q * 8 + 32 * ks);
                tacc[tj] = __builtin_amdgcn_mfma_f32_16x16x32_bf16(aQ[ks], bK, tacc[tj], 0, 0, 0);
            }
        }
    }

    // ---- phase 3a: S1 = softmax over col-pooled rows (32 logits/row) ----
    {
        float p[4][4], e[4][4], mx[4], s[4];
        #pragma unroll
        for (int r = 0; r < 4; ++r) mx[r] = -1e30f;
        #pragma unroll
        for (int t = 0; t < 4; ++t)
            #pragma unroll
            for (int r = 0; r < 4; ++r) {
                float v  = tacc[t][r];
                float pv = (v + __shfl_xor(v, 1)) * (0.5f * SCALE);  // pooled pair
                p[t][r] = pv;
                mx[r]   = fmaxf(mx[r], pv);
            }
        #pragma unroll
        for (int r = 0; r < 4; ++r) {
            #pragma unroll
            for (int d = 1; d < 16; d <<= 1)
                mx[r] = fmaxf(mx[r], __shfl_xor(mx[r], d));
            s[r] = 0.f;
        }
        #pragma unroll
        for (int t = 0; t < 4; ++t)
            #pragma unroll
            for (int r = 0; r < 4; ++r) {
                e[t][r] = __expf(p[t][r] - mx[r]);
                s[r] += e[t][r];
            }
        #pragma unroll
        for (int r = 0; r < 4; ++r) {
            #pragma unroll
            for (int d = 1; d < 16; d <<= 1)
                s[r] += __shfl_xor(s[r], d);
            s[r] = 2.0f / s[r];   // each jp counted twice in the lane reduction
        }
        if (!(l & 1)) {
            int jc = m >> 1;      // pooled col within tile (0..7)
            #pragma unroll
            for (int t = 0; t < 4; ++t)
                #pragma unroll
                for (int r = 0; r < 4; ++r)
                    S1b[(16 * w + q * 4 + r) * 40 + t * 8 + jc] =
                        __float2bfloat16(e[t][r] * s[r]);
        }
    }

    // ---- phase 3b: S2 = softmax over rows of row-pooled T (64 logits/row) ----
    {
        float p2[4][2], e2[4][2], mx[2], s[2];
        #pragma unroll
        for (int h = 0; h < 2; ++h) mx[h] = -1e30f;
        #pragma unroll
        for (int t = 0; t < 4; ++t)
            #pragma unroll
            for (int h = 0; h < 2; ++h) {
                float pv = (tacc[t][2 * h] + tacc[t][2 * h + 1]) * (0.5f * SCALE);
                p2[t][h] = pv;
                mx[h]    = fmaxf(mx[h], pv);
            }
        #pragma unroll
        for (int h = 0; h < 2; ++h) {
            #pragma unroll
            for (int d = 1; d < 16; d <<= 1)
                mx[h] = fmaxf(mx[h], __shfl_xor(mx[h], d));
            s[h] = 0.f;
        }
        #pragma unroll
        for (int t = 0; t < 4; ++t)
            #pragma unroll
            for (int h = 0; h < 2; ++h) {
                e2[t][h] = __expf(p2[t][h] - mx[h]);
                s[h] += e2[t][h];
            }
        #pragma unroll
        for (int h = 0; h < 2; ++h) {
            #pragma unroll
            for (int d = 1; d < 16; d <<= 1)
                s[h] += __shfl_xor(s[h], d);
            s[h] = 1.0f / s[h];
        }
        #pragma unroll
        for (int t = 0; t < 4; ++t)
            #pragma unroll
            for (int h = 0; h < 2; ++h)
                S2b[(8 * w + q * 2 + h) * 72 + t * 16 + m] =
                    __float2bfloat16(e2[t][h] * s[h]);
    }
    __syncthreads();   // VT, S1b, S2b now visible to all waves

    // ---- phase 4: KVT[ph][ip] = sum_j VT[ph][j] * S2[ip][j] ----
    {
        short8 aV[2];
        #pragma unroll
        for (int ks = 0; ks < 2; ++ks)
            aV[ks] = *(const short8*)&VT[(16 * w + m) * 72 + q * 8 + 32 * ks];
        #pragma unroll
        for (int tn = 0; tn < 2; ++tn) {
            f32x4 kacc = {0.f, 0.f, 0.f, 0.f};
            #pragma unroll
            for (int ks = 0; ks < 2; ++ks) {
                short8 bS = *(const short8*)&S2b[(16 * tn + m) * 72 + q * 8 + 32 * ks];
                kacc = __builtin_amdgcn_mfma_f32_16x16x32_bf16(aV[ks], bS, kacc, 0, 0, 0);
            }
            #pragma unroll
            for (int r = 0; r < 4; ++r)
                KVT[(16 * w + q * 4 + r) * 40 + 16 * tn + m] = __float2bfloat16(kacc[r]);
        }
    }
    __syncthreads();   // KVT visible; all VT reads complete

    // ---- phase 5: out[i][ph] = sum_jp S1[i][jp] * KVT[ph][jp] ----
    f32x4 oacc[4];
    {
        short8 aS = *(const short8*)&S1b[(16 * w + m) * 40 + q * 8];
        #pragma unroll
        for (int tn = 0; tn < 4; ++tn) {
            short8 bKV = *(const short8*)&KVT[(16 * tn + m) * 40 + q * 8];
            f32x4 z = {0.f, 0.f, 0.f, 0.f};
            oacc[tn] = __builtin_amdgcn_mfma_f32_16x16x32_bf16(aS, bKV, z, 0, 0, 0);
        }
    }

    // ---- phase 6: stage out (bf16) into VT region, then coalesced store ----
    {
        bf16* OutS = VT;   // [64][72], VT dead (all reads before last barrier)
        #pragma unroll
        for (int tn = 0; tn < 4; ++tn)
            #pragma unroll
            for (int r = 0; r < 4; ++r)
                OutS[(16 * w + q * 4 + r) * 72 + 16 * tn + m] = __float2bfloat16(oacc[tn][r]);
        __syncthreads();
        uint* Og = (uint*)(Os + base);
        #pragma unroll
        for (int v = 0; v < 8; ++v) {
            int e  = tid + 256 * v;    // 0..2047
            int i  = e >> 5;
            int pp = e & 31;
            Og[e] = *(uint*)&OutS[i * 72 + 2 * pp];
        }
    }
}

// ---------------------------------------------------------------------------
// Kernel 3: spatial [B,C,N] (bf16) -> [B,N,C] (f32) tiled transpose.
// ---------------------------------------------------------------------------
__global__ __launch_bounds__(256) void unspat_kernel(
    const bf16* __restrict__ Os, float* __restrict__ out)
{
    __shared__ float t[32][65];
    const int b  = blockIdx.z;
    const int c0 = blockIdx.y * 32;
    const int n0 = blockIdx.x * 64;
    const int tx = threadIdx.x & 31;
    const int ty = threadIdx.x >> 5;
    const bf162* src = (const bf162*)(Os + ((size_t)b * NC + c0) * NN + n0);
    #pragma unroll
    for (int r = 0; r < 4; ++r) {
        int cc = ty + r * 8;
        float2 f = __bfloat1622float2(src[(size_t)cc * (NN/2) + tx]);
        t[cc][2*tx] = f.x; t[cc][2*tx+1] = f.y;
    }
    __syncthreads();
    float* dst = out + ((size_t)b * NN + n0) * NC + c0;
    #pragma unroll
    for (int r = 0; r < 8; ++r) {
        int nn = ty + r * 8;
        dst[(size_t)nn * NC + tx] = t[tx][nn];
    }
}

// ---------------------------------------------------------------------------
extern "C" void kernel_launch(void* const* d_in, const int* in_sizes, int n_in,
                              void* d_out, int out_size, void* d_ws, size_t ws_size,
                              hipStream_t stream)
{
    const float* x  = (const float*)d_in[0];
    const float* Wq = (const float*)d_in[1];
    const float* bq = (const float*)d_in[2];
    const float* Wk = (const float*)d_in[3];
    const float* bk = (const float*)d_in[4];
    const float* Wv = (const float*)d_in[5];
    const float* bv = (const float*)d_in[6];
    float* out = (float*)d_out;

    const size_t S = (size_t)NB * NC * NN;   // 33,554,432 elems per tensor
    bf16* Qb = (bf16*)d_ws;                  // ws >= 3*S*2 = 201,326,592 B
    bf16* Kb = Qb + S;
    bf16* Vb = Kb + S;
    bf16* xb = (bf16*)d_out;                 // dead until unspat overwrites

    cast_x_kernel<<<dim3((NB * NN * NC) / (256 * 8)), 256, 0, stream>>>(x, xb);
    proj_mfma<<<dim3(12, (NB * NN) / 128), 256, 0, stream>>>(
        xb, Wq, bq, Wk, bk, Wv, bv, Qb, Kb, Vb);
    // attention writes its output into the Q region (each block's slice is
    // disjoint and its Q reads complete before its writes).
    attn_mfma<<<dim3(NB * NC), 256, 0, stream>>>(Qb, Kb, Vb, Qb);
    unspat_kernel<<<dim3(NN / 64, NC / 32, NB), 256, 0, stream>>>(Qb, out);
}